// Round 24
// baseline (188.046 us; speedup 1.0000x reference)
//
#include <hip/hip_runtime.h>
#include <hip/hip_bf16.h>
#include <math.h>

#define N_IN 85680
#define PRE_K 5000
#define POST_K 750
#define NW 79            // ceil(PRE_K/64) words
#define NPAD 5056        // NW*64
#define HSIZE 8192       // linear buckets over score-bit range (0.02, +inf)
#define CAND_MAX 8192
#define CONF_THR 0.02f
#define NMS_THR 0.4f
#define BITS_THR 0x3CA3D70Bu  // bits of smallest float > 0.02f
#define ZBYTES 66624     // zeroed workspace prefix (hist+bfill+bsel+validm)
#define WLDS 20          // words staged in LDS (1280 boxes; exit fires ~word 15)
#define NCHUNK 110       // total 128-u64 staging chunks = sum ceil((1280-64k)/128)

typedef unsigned int u32;
typedef unsigned long long u64;

// column-major triangle-packed mask: word k's segment starts at cbase(k), holds
// rows 64k..NPAD-1. cbase(k) = k*(5088 - 32k)  [u64 units]; cbase(79)=202240.
__device__ __forceinline__ int cbase(int k) { return k * (5088 - 32 * k); }

// LDS sub-triangle layout: word k's segment (rows 64k..1279, padded to 128-u64
// chunks) starts at 128*S(k), S(2m)=m(21-m), S(2m+1)=m(21-m)+(10-m). S(20)=110.
__device__ __forceinline__ int ldsoff(int k) {
    int m = k >> 1;
    return 128 * (m * (21 - m) + ((k & 1) ? (10 - m) : 0));
}

// opacity barrier: prevents FMA contraction so f32 math bit-matches numpy ref
__device__ __forceinline__ float opaquef(float x) { asm volatile("" : "+v"(x)); return x; }

// monotone bucket of a score's float bits (score > CONF_THR guaranteed)
__device__ __forceinline__ u32 bucket_of(u32 bits) {
    u32 b = (bits - BITS_THR) >> 13;
    return b >= HSIZE ? (HSIZE - 1) : b;
}

// async global->LDS 16B: global src is PER-LANE, LDS dest is wave-uniform base
// (HW writes base + lane*16)
__device__ __forceinline__ void gload_lds16(const void* g, void* l) {
    __builtin_amdgcn_global_load_lds(
        (const __attribute__((address_space(1))) void*)g,
        (__attribute__((address_space(3))) void*)l, 16, 0, 0);
}

// ---------------- zero the accumulator region ----------------
__global__ __launch_bounds__(256) void zero_kernel(u32* __restrict__ p) {
    int i = blockIdx.x * 256 + threadIdx.x;
    if (i < ZBYTES / 4) p[i] = 0u;
}

// ---------------- histogram of valid score buckets (multi-block) ----------------
__global__ __launch_bounds__(256) void hist_kernel(const float2* __restrict__ conf2,
                                                   u32* __restrict__ hist) {
    __shared__ u32 h[HSIZE];
    for (int b = threadIdx.x; b < HSIZE; b += 256) h[b] = 0u;
    __syncthreads();
    int i = blockIdx.x * 256 + threadIdx.x;
    if (i < N_IN) {
        float s = conf2[i].y;
        if (s > CONF_THR) atomicAdd(&h[bucket_of(__float_as_uint(s))], 1u);
    }
    __syncthreads();
    for (int b = threadIdx.x; b < HSIZE; b += 256) {
        u32 v = h[b];
        if (v) atomicAdd(&hist[b], v);
    }
}

// ---------------- suffix-scan: bstart[b] = #keys in buckets > b; bsel ----------
__global__ __launch_bounds__(1024) void scan_kernel(const u32* __restrict__ hist,
                                                    u32* __restrict__ bsel,
                                                    u32* __restrict__ bstart) {
    __shared__ u32 tot[1024];
    int c = threadIdx.x;
    u32 lh[8];
    u32 t = 0;
#pragma unroll
    for (int k = 0; k < 8; ++k) { lh[k] = hist[c * 8 + k]; t += lh[k]; }
    tot[c] = t;
    __syncthreads();
    for (int d = 1; d < 1024; d <<= 1) {
        u32 v = tot[c] + ((c + d < 1024) ? tot[c + d] : 0u);
        __syncthreads();
        tot[c] = v;
        __syncthreads();
    }
    u32 above = (c + 1 < 1024) ? tot[c + 1] : 0u;
    u32 s = above;
    for (int k = 7; k >= 0; --k) { bstart[c * 8 + k] = s; s += lh[k]; }
    if (above < PRE_K && above + t >= PRE_K) {
        u32 cum = above;
        for (int k = 7; k >= 0; --k) {
            cum += lh[k];
            if (cum >= PRE_K) { bsel[0] = (u32)(c * 8 + k); break; }
        }
    }
    if (c == 0 && tot[0] < PRE_K) bsel[0] = 0u;
}

// ---------------- scatter candidates bucket-grouped ----------------
__global__ __launch_bounds__(256) void compact_kernel(const float2* __restrict__ conf2,
                                                      const u32* __restrict__ bsel,
                                                      const u32* __restrict__ bstart,
                                                      u32* __restrict__ bfill,
                                                      u64* __restrict__ cand) {
    int i = blockIdx.x * 256 + threadIdx.x;
    if (i >= N_IN) return;
    float sc = conf2[i].y;
    if (!(sc > CONF_THR)) return;
    u32 bits = __float_as_uint(sc);
    u32 b = bucket_of(bits);
    if (b < bsel[0]) return;
    u32 pos = bstart[b] + atomicAdd(&bfill[b], 1u);
    if (pos < CAND_MAX) cand[pos] = ((u64)bits << 32) | (u64)(u32)(~(u32)i);
}

// ---------------- fused: exact rank within bucket + decode -> rows/boxes/validm ----------------
__global__ __launch_bounds__(256) void rankdec_kernel(const u64* __restrict__ cand,
                                                      const u32* __restrict__ bstart,
                                                      const u32* __restrict__ bfill,
                                                      const u32* __restrict__ bsel,
                                                      const float4* __restrict__ loc4,
                                                      const float4* __restrict__ pri4,
                                                      const float* __restrict__ lmk,
                                                      const int* __restrict__ imw,
                                                      const int* __restrict__ imh,
                                                      float4* __restrict__ rows4,
                                                      float4* __restrict__ boxes,
                                                      u64* __restrict__ validm) {
    u32 bs = bsel[0];
    u32 total = bstart[bs] + bfill[bs];
    if (total > CAND_MAX) total = CAND_MAX;
    float W = (float)(*imw), H = (float)(*imh);
    for (u32 s = blockIdx.x * blockDim.x + threadIdx.x; s < total;
         s += gridDim.x * blockDim.x) {
        u64 key = cand[s];
        u32 b = bucket_of((u32)(key >> 32));
        u32 st = bstart[b];
        u32 en = st + bfill[b];
        if (en > CAND_MAX) en = CAND_MAX;
        u32 r = st;
        for (u32 j = st; j < en; ++j) r += (cand[j] > key) ? 1u : 0u;
        if (r >= PRE_K) continue;
        u32 i = ~(u32)key;
        float score = __uint_as_float((u32)(key >> 32));
        float4 L = loc4[i];
        float4 P = pri4[i];
        float cx = P.x + opaquef((L.x * 0.1f) * P.z);
        float cy = P.y + opaquef((L.y * 0.1f) * P.w);
        float bw = P.z * (float)exp((double)(L.z * 0.2f));
        float bh = P.w * (float)exp((double)(L.w * 0.2f));
        float hw = opaquef(bw * 0.5f), hh = opaquef(bh * 0.5f);
        float x0 = (cx - hw) * W, y0 = (cy - hh) * H;
        float x1 = (cx + hw) * W, y1 = (cy + hh) * H;
        boxes[r] = make_float4(x0, y0, x1, y1);
        float lm[10];
#pragma unroll
        for (int p = 0; p < 5; ++p) {
            float2 q = ((const float2*)lmk)[(size_t)i * 5 + p];
            lm[2 * p]     = (P.x + opaquef((q.x * 0.1f) * P.z)) * W;
            lm[2 * p + 1] = (P.y + opaquef((q.y * 0.1f) * P.w)) * H;
        }
        float4* row = rows4 + (size_t)r * 4;
        row[0] = make_float4(x0, y0, x1, y1);
        row[1] = make_float4(score, lm[0], lm[1], lm[2]);
        row[2] = make_float4(lm[3], lm[4], lm[5], lm[6]);
        row[3] = make_float4(lm[7], lm[8], lm[9], 0.f);
        atomicOr(&validm[r >> 6], 1ull << (r & 63));
    }
}

// ---------------- symmetric IoU bitmask, column-major triangle-packed ----------------
__global__ __launch_bounds__(256) void mask_kernel(const float4* __restrict__ boxes,
                                                   u64* __restrict__ cmask) {
    __shared__ float4 cb4[4][64];
    int wv = threadIdx.x >> 6, t = threadIdx.x & 63;
    int t64 = blockIdx.x * 4 + wv;
    if (t64 >= NW * (NW + 1) / 2) return;
    // flat t64 = rc*(rc+1)/2 + cc, cc <= rc
    int rc = (int)((sqrtf(8.0f * (float)t64 + 1.0f) - 1.0f) * 0.5f);
    while ((rc + 1) * (rc + 2) / 2 <= t64) ++rc;
    while (rc * (rc + 1) / 2 > t64) --rc;
    int cc = t64 - rc * (rc + 1) / 2;
    cb4[wv][t] = boxes[cc * 64 + t];
    int i = rc * 64 + t;
    float4 bi = boxes[i];
    float areai = (bi.z - bi.x) * (bi.w - bi.y);
    u64 word = 0ull;
#pragma unroll 4
    for (int k = 0; k < 64; ++k) {
        float4 bj = cb4[wv][k];      // same-wave LDS RAW: compiler inserts lgkmcnt
        float areaj = (bj.z - bj.x) * (bj.w - bj.y);
        float ltx = fmaxf(bi.x, bj.x), lty = fmaxf(bi.y, bj.y);
        float rbx = fminf(bi.z, bj.z), rby = fminf(bi.w, bj.w);
        float wx = fmaxf(rbx - ltx, 0.f), wy = fmaxf(rby - lty, 0.f);
        float inter = opaquef(wx * wy);
        float uni = fmaxf(areai + areaj - inter, 1e-12f);
        float iou = inter / uni;
        if (iou > NMS_THR) word |= (1ull << k);
    }
    if (i < PRE_K) cmask[(size_t)(cbase(cc) + (i - 64 * cc))] = word;
}

// coalesced column load: word k, global row q
#define FC(k, q) cmask[(size_t)(cbase(k) + (q) - 64 * (k))]

// exact greedy within-word solve, LEVEL-WISE (one DAG level per iteration)
__device__ __forceinline__ u64 nms_solve(u64 valw, u64 sup, u64 dlow) {
    u64 keep = valw & ~__ballot(sup != 0ull);
    for (;;) {
        u64 conm = __ballot((dlow & keep) != 0ull);
        u64 cm = conm & keep;
        if (cm == 0ull) break;
        u64 U = keep & ~conm;
        u64 rem = __ballot((dlow & U) != 0ull) & keep;
        keep &= ~rem;
    }
    return keep;
}

// ---------------- LDS-staged exact greedy NMS + fused scatter (1 block) ----------
// v10: stage the WLDS=20-word sub-triangle (rows<1280, 113KB) into LDS via ~110
// async global_load_lds instructions from 8 waves -> ONE vmcnt wait; then wave 0
// solves all 20 words sequentially from LDS (no handshakes, no spinning, no
// global latency on the chain). The 750-keep exit fires ~word 15 (R18/R19 FETCH
// evidence), so words 20.. take a global-memory fallback that never executes on
// this input but keeps the kernel exact for any data.
__global__ __launch_bounds__(512) void reduce_scatter_kernel(const u64* __restrict__ cmask,
                                                             const u64* __restrict__ validm,
                                                             const float* __restrict__ rows,
                                                             float* __restrict__ out) {
    int tid = threadIdx.x;
    int g = tid >> 6, lane = tid & 63;
    __shared__ __align__(16) u64 tri[14080];   // 112,640 B staged sub-triangle
    __shared__ u64 keepAll[96];
    __shared__ u64 validL[WLDS];
    __shared__ u32 wpref[97];
    for (int k = tid; k < 96; k += 512) keepAll[k] = 0ull;
    __syncthreads();   // keepAll zero visible before solve
    u64 lmask = (1ull << lane) - 1ull;

    // ---- stage: flat chunk j -> (word k, chunk r); chunks(k) = (21-k)>>1 ----
    for (int j = g; j < NCHUNK; j += 8) {
        int k = 0, r = j;
        while (r >= ((21 - k) >> 1)) { r -= (21 - k) >> 1; ++k; }
        int off64 = ldsoff(k) + r * 128;
        const char* gsrc = (const char*)(cmask + (size_t)cbase(k) + (size_t)r * 128)
                           + (size_t)lane * 16;
        gload_lds16(gsrc, (char*)tri + (size_t)off64 * 8);
    }
    if (g == 7 && lane < WLDS) validL[lane] = validm[lane];
    asm volatile("s_waitcnt vmcnt(0)" ::: "memory");
    __syncthreads();

    // ---- solve: wave 0 only, sequential words, all data in LDS ----
    if (g == 0) {
        u32 totK = 0;
        int w = 0;
        for (; w < WLDS; ++w) {
            int q = 64 * w + lane;
            u64 sup = 0ull;
            for (int w2 = 0; w2 < w; ++w2)
                sup |= keepAll[w2] & tri[ldsoff(w2) + q - 64 * w2];
            u64 dlow = tri[ldsoff(w) + lane] & lmask;
            u64 keep = nms_solve(validL[w], sup, dlow);
            if (lane == 0) keepAll[w] = keep;
            totK += (u32)__popcll(keep);     // ballot result: wave-uniform
            if (totK >= POST_K) break;       // later keeps: rank >= 750 (stay 0)
        }
        // exact fallback (never taken on this input): words WLDS..NW-1 via global
        if (totK < POST_K) {
            for (w = WLDS; w < NW; ++w) {
                int q = 64 * w + lane;
                u64 sup = 0ull;
                for (int w2 = 0; w2 < w; ++w2) sup |= keepAll[w2] & FC(w2, q);
                u64 dlow = FC(w, q) & lmask;   // diag word (row q, col w)
                u64 keep = nms_solve(validm[w], sup, dlow);
                if (lane == 0) keepAll[w] = keep;
                totK += (u32)__popcll(keep);
                if (totK >= POST_K) break;
            }
        }
    }
    __syncthreads();

    // ---- word-prefix ranks + scatter ----
    if (tid == 0) {
        u32 s = 0;
        for (int w = 0; w < NW; ++w) { wpref[w] = s; s += (u32)__popcll(keepAll[w]); }
        wpref[NW] = s;
    }
    __syncthreads();
    u32 totk = wpref[NW]; if (totk > POST_K) totk = POST_K;
    for (int r = tid; r < PRE_K; r += 512) {
        int w = r >> 6, b = r & 63;
        u64 kw = keepAll[w];
        if ((kw >> b) & 1ull) {
            u32 rank = wpref[w] + (u32)__popcll(kw & ((1ull << b) - 1ull));
            if (rank < POST_K) {
                const float* src = rows + (size_t)r * 16;
                float* dst = out + (size_t)rank * 15;
#pragma unroll
                for (int c2 = 0; c2 < 15; ++c2) dst[c2] = src[c2];
            }
        }
    }
    for (int r = (int)totk + tid; r < POST_K; r += 512) {
        float* dst = out + (size_t)r * 15;
#pragma unroll
        for (int c2 = 0; c2 < 15; ++c2) dst[c2] = 0.f;
    }
}

extern "C" void kernel_launch(void* const* d_in, const int* in_sizes, int n_in,
                              void* d_out, int out_size, void* d_ws, size_t ws_size,
                              hipStream_t stream) {
    const float* loc = (const float*)d_in[0];
    const float2* conf2 = (const float2*)d_in[1];
    const float* lmk = (const float*)d_in[2];
    const float* pri = (const float*)d_in[3];
    const int* imw = (const int*)d_in[4];
    const int* imh = (const int*)d_in[5];
    float* out = (float*)d_out;
    char* base = (char*)d_ws;

    // workspace layout (bytes); total 2,184,768 (< 3,808,896 proven in R3-R23)
    u32* hist   = (u32*)(base + 0);         //  32768  [zeroed by zero_kernel]
    u32* bfill  = (u32*)(base + 32768);     //  32768  [zeroed]
    u32* bsel   = (u32*)(base + 65536);     //  64     [zeroed]
    u64* validm = (u64*)(base + 65600);     //  1024   [zeroed]  -> zero [0,66624)
    u32* bstart = (u32*)(base + 67648);     //  32768
    u64* cand   = (u64*)(base + 100416);    //  65536
    float* rows = (float*)(base + 165952);  //  320000 (5000 x 16)
    float4* boxes = (float4*)(base + 485952); // 80896 (NPAD x 16)
    u64* cmask  = (u64*)(base + 566848);    //  1617920 (202240 u64, triangle-packed)

    zero_kernel<<<(ZBYTES / 4 + 255) / 256, 256, 0, stream>>>((u32*)base);

    hist_kernel<<<(N_IN + 255) / 256, 256, 0, stream>>>(conf2, hist);
    scan_kernel<<<1, 1024, 0, stream>>>(hist, bsel, bstart);
    compact_kernel<<<(N_IN + 255) / 256, 256, 0, stream>>>(conf2, bsel, bstart, bfill, cand);
    rankdec_kernel<<<48, 256, 0, stream>>>(cand, bstart, bfill, bsel, (const float4*)loc,
                                           (const float4*)pri, lmk, imw, imh,
                                           (float4*)rows, boxes, validm);
    mask_kernel<<<(NW * (NW + 1) / 2 + 3) / 4, 256, 0, stream>>>(boxes, cmask);
    reduce_scatter_kernel<<<1, 512, 0, stream>>>(cmask, validm, rows, out);
}

// Round 25
// 93.064 us; speedup vs baseline: 2.0206x; 2.0206x over previous
//
#include <hip/hip_runtime.h>
#include <hip/hip_bf16.h>
#include <math.h>

#define N_IN 85680
#define PRE_K 5000
#define POST_K 750
#define NW 79            // ceil(PRE_K/64) words
#define NPAD 5056        // NW*64
#define HSIZE 8192       // linear buckets over score-bit range (0.02, +inf)
#define CAND_MAX 8192
#define CONF_THR 0.02f
#define NMS_THR 0.4f
#define BITS_THR 0x3CA3D70Bu  // bits of smallest float > 0.02f
#define NGRP 20          // ceil(NW/4) word-groups for the GS chain
#define ZBYTES 66624     // zeroed workspace prefix (hist+bfill+bsel+validm)

typedef unsigned int u32;
typedef unsigned long long u64;

// column-major triangle-packed mask: word k's segment starts at cbase(k), holds
// rows 64k..NPAD-1. cbase(k) = k*(5088 - 32k)  [u64 units]; cbase(79)=202240.
__device__ __forceinline__ int cbase(int k) { return k * (5088 - 32 * k); }

// opacity barrier: prevents FMA contraction so f32 math bit-matches numpy ref
__device__ __forceinline__ float opaquef(float x) { asm volatile("" : "+v"(x)); return x; }

// monotone bucket of a score's float bits (score > CONF_THR guaranteed)
__device__ __forceinline__ u32 bucket_of(u32 bits) {
    u32 b = (bits - BITS_THR) >> 13;
    return b >= HSIZE ? (HSIZE - 1) : b;
}

// ---------------- zero the accumulator region ----------------
__global__ __launch_bounds__(256) void zero_kernel(u32* __restrict__ p) {
    int i = blockIdx.x * 256 + threadIdx.x;
    if (i < ZBYTES / 4) p[i] = 0u;
}

// ---------------- histogram of valid score buckets (multi-block) ----------------
__global__ __launch_bounds__(256) void hist_kernel(const float2* __restrict__ conf2,
                                                   u32* __restrict__ hist) {
    __shared__ u32 h[HSIZE];
    for (int b = threadIdx.x; b < HSIZE; b += 256) h[b] = 0u;
    __syncthreads();
    int i = blockIdx.x * 256 + threadIdx.x;
    if (i < N_IN) {
        float s = conf2[i].y;
        if (s > CONF_THR) atomicAdd(&h[bucket_of(__float_as_uint(s))], 1u);
    }
    __syncthreads();
    for (int b = threadIdx.x; b < HSIZE; b += 256) {
        u32 v = h[b];
        if (v) atomicAdd(&hist[b], v);
    }
}

// ---------------- suffix-scan: bstart[b] = #keys in buckets > b; bsel ----------
__global__ __launch_bounds__(1024) void scan_kernel(const u32* __restrict__ hist,
                                                    u32* __restrict__ bsel,
                                                    u32* __restrict__ bstart) {
    __shared__ u32 tot[1024];
    int c = threadIdx.x;
    u32 lh[8];
    u32 t = 0;
#pragma unroll
    for (int k = 0; k < 8; ++k) { lh[k] = hist[c * 8 + k]; t += lh[k]; }
    tot[c] = t;
    __syncthreads();
    for (int d = 1; d < 1024; d <<= 1) {
        u32 v = tot[c] + ((c + d < 1024) ? tot[c + d] : 0u);
        __syncthreads();
        tot[c] = v;
        __syncthreads();
    }
    u32 above = (c + 1 < 1024) ? tot[c + 1] : 0u;
    u32 s = above;
    for (int k = 7; k >= 0; --k) { bstart[c * 8 + k] = s; s += lh[k]; }
    if (above < PRE_K && above + t >= PRE_K) {
        u32 cum = above;
        for (int k = 7; k >= 0; --k) {
            cum += lh[k];
            if (cum >= PRE_K) { bsel[0] = (u32)(c * 8 + k); break; }
        }
    }
    if (c == 0 && tot[0] < PRE_K) bsel[0] = 0u;
}

// ---------------- scatter candidates bucket-grouped ----------------
__global__ __launch_bounds__(256) void compact_kernel(const float2* __restrict__ conf2,
                                                      const u32* __restrict__ bsel,
                                                      const u32* __restrict__ bstart,
                                                      u32* __restrict__ bfill,
                                                      u64* __restrict__ cand) {
    int i = blockIdx.x * 256 + threadIdx.x;
    if (i >= N_IN) return;
    float sc = conf2[i].y;
    if (!(sc > CONF_THR)) return;
    u32 bits = __float_as_uint(sc);
    u32 b = bucket_of(bits);
    if (b < bsel[0]) return;
    u32 pos = bstart[b] + atomicAdd(&bfill[b], 1u);
    if (pos < CAND_MAX) cand[pos] = ((u64)bits << 32) | (u64)(u32)(~(u32)i);
}

// ---------------- fused: exact rank within bucket + decode -> rows/boxes/validm ----------------
__global__ __launch_bounds__(256) void rankdec_kernel(const u64* __restrict__ cand,
                                                      const u32* __restrict__ bstart,
                                                      const u32* __restrict__ bfill,
                                                      const u32* __restrict__ bsel,
                                                      const float4* __restrict__ loc4,
                                                      const float4* __restrict__ pri4,
                                                      const float* __restrict__ lmk,
                                                      const int* __restrict__ imw,
                                                      const int* __restrict__ imh,
                                                      float4* __restrict__ rows4,
                                                      float4* __restrict__ boxes,
                                                      u64* __restrict__ validm) {
    u32 bs = bsel[0];
    u32 total = bstart[bs] + bfill[bs];
    if (total > CAND_MAX) total = CAND_MAX;
    float W = (float)(*imw), H = (float)(*imh);
    for (u32 s = blockIdx.x * blockDim.x + threadIdx.x; s < total;
         s += gridDim.x * blockDim.x) {
        u64 key = cand[s];
        u32 b = bucket_of((u32)(key >> 32));
        u32 st = bstart[b];
        u32 en = st + bfill[b];
        if (en > CAND_MAX) en = CAND_MAX;
        u32 r = st;
        for (u32 j = st; j < en; ++j) r += (cand[j] > key) ? 1u : 0u;
        if (r >= PRE_K) continue;
        u32 i = ~(u32)key;
        float score = __uint_as_float((u32)(key >> 32));
        float4 L = loc4[i];
        float4 P = pri4[i];
        float cx = P.x + opaquef((L.x * 0.1f) * P.z);
        float cy = P.y + opaquef((L.y * 0.1f) * P.w);
        float bw = P.z * (float)exp((double)(L.z * 0.2f));
        float bh = P.w * (float)exp((double)(L.w * 0.2f));
        float hw = opaquef(bw * 0.5f), hh = opaquef(bh * 0.5f);
        float x0 = (cx - hw) * W, y0 = (cy - hh) * H;
        float x1 = (cx + hw) * W, y1 = (cy + hh) * H;
        boxes[r] = make_float4(x0, y0, x1, y1);
        float lm[10];
#pragma unroll
        for (int p = 0; p < 5; ++p) {
            float2 q = ((const float2*)lmk)[(size_t)i * 5 + p];
            lm[2 * p]     = (P.x + opaquef((q.x * 0.1f) * P.z)) * W;
            lm[2 * p + 1] = (P.y + opaquef((q.y * 0.1f) * P.w)) * H;
        }
        float4* row = rows4 + (size_t)r * 4;
        row[0] = make_float4(x0, y0, x1, y1);
        row[1] = make_float4(score, lm[0], lm[1], lm[2]);
        row[2] = make_float4(lm[3], lm[4], lm[5], lm[6]);
        row[3] = make_float4(lm[7], lm[8], lm[9], 0.f);
        atomicOr(&validm[r >> 6], 1ull << (r & 63));
    }
}

// ---------------- symmetric IoU bitmask, column-major triangle-packed ----------------
__global__ __launch_bounds__(256) void mask_kernel(const float4* __restrict__ boxes,
                                                   u64* __restrict__ cmask) {
    __shared__ float4 cb4[4][64];
    int wv = threadIdx.x >> 6, t = threadIdx.x & 63;
    int t64 = blockIdx.x * 4 + wv;
    if (t64 >= NW * (NW + 1) / 2) return;
    // flat t64 = rc*(rc+1)/2 + cc, cc <= rc
    int rc = (int)((sqrtf(8.0f * (float)t64 + 1.0f) - 1.0f) * 0.5f);
    while ((rc + 1) * (rc + 2) / 2 <= t64) ++rc;
    while (rc * (rc + 1) / 2 > t64) --rc;
    int cc = t64 - rc * (rc + 1) / 2;
    cb4[wv][t] = boxes[cc * 64 + t];
    int i = rc * 64 + t;
    float4 bi = boxes[i];
    float areai = (bi.z - bi.x) * (bi.w - bi.y);
    u64 word = 0ull;
#pragma unroll 4
    for (int k = 0; k < 64; ++k) {
        float4 bj = cb4[wv][k];      // same-wave LDS RAW: compiler inserts lgkmcnt
        float areaj = (bj.z - bj.x) * (bj.w - bj.y);
        float ltx = fmaxf(bi.x, bj.x), lty = fmaxf(bi.y, bj.y);
        float rbx = fminf(bi.z, bj.z), rby = fminf(bi.w, bj.w);
        float wx = fmaxf(rbx - ltx, 0.f), wy = fmaxf(rby - lty, 0.f);
        float inter = opaquef(wx * wy);
        float uni = fmaxf(areai + areaj - inter, 1e-12f);
        float iou = inter / uni;
        if (iou > NMS_THR) word |= (1ull << k);
    }
    if (i < PRE_K) cmask[(size_t)(cbase(cc) + (i - 64 * cc))] = word;
}

// coalesced column load: word k, global row q
#define FC(k, q) cmask[(size_t)(cbase(k) + (q) - 64 * (k))]

// guarded fold-batch load: column d+j (0 if beyond w0), row qr
#define LDC(j, r, d) ((((d) + (j)) < w0) ? FC((d) + (j), q##r) : 0ull)

// tight busy-poll on relaxed group counter; sentinel (> NGRP) -> dead
#define WAITG(need)                                                                   \
    for (;;) {                                                                        \
        u32 d_ = __hip_atomic_load(&doneCnt, __ATOMIC_RELAXED,                        \
                                   __HIP_MEMORY_SCOPE_WORKGROUP);                     \
        if (d_ > (u32)NGRP) { dead = true; break; }                                   \
        if (d_ >= (u32)(need)) break;                                                 \
    }                                                                                 \
    asm volatile("" ::: "memory");

// exact greedy within-word solve, LEVEL-WISE (one DAG level per iteration)
__device__ __forceinline__ u64 nms_solve(u64 valw, u64 sup, u64 dlow) {
    u64 keep = valw & ~__ballot(sup != 0ull);
    for (;;) {
        u64 conm = __ballot((dlow & keep) != 0ull);
        u64 cm = conm & keep;
        if (cm == 0ull) break;
        u64 U = keep & ~conm;
        u64 rem = __ballot((dlow & U) != 0ull) & keep;
        keep &= ~rem;
    }
    return keep;
}

// ---------------- exact one-pass GS NMS + fused scatter (1 block, 8 waves) ----------
// v11 = R23 structure with the fold double-buffer widened 2 -> 4 columns per
// batch (aligned; 32 named u64 buffer regs). In-flight fold loads per wave
// double (8 -> 16; 8 waves ~ 128 outstanding) — the reduce is a latency-bound
// ~550KB stream (exit ~word 45, R24 post-mortem), so MLP is the lever.
__global__ __launch_bounds__(512) void reduce_scatter_kernel(const u64* __restrict__ cmask,
                                                             const u64* __restrict__ validm,
                                                             const float* __restrict__ rows,
                                                             float* __restrict__ out) {
    int tid = threadIdx.x;
    int g = tid >> 6, lane = tid & 63;
    __shared__ u64 keepAll[96];
    __shared__ u32 totG[32];
    __shared__ u32 doneCnt;   // # finalized groups; NGRP+9 = early-exit sentinel
    __shared__ u32 wpref[97];
    for (int k = tid; k < 96; k += 512) keepAll[k] = 0ull;
    if (tid == 0) doneCnt = 0u;
    __syncthreads();
    u64 lmask = (1ull << lane) - 1ull;   // bits strictly below my lane

    for (int s = 0; s < 3; ++s) {
        int G = s * 8 + g;
        if (G >= NGRP) break;
        int w0 = 4 * G;
        int nwg = NW - w0; if (nwg > 4) nwg = 4;       // 4, or 3 for the last group
        int q0 = 64 * w0 + lane;
        int q1 = q0 + 64;
        int q2 = q0 + 128;
        int q3 = (nwg > 3) ? (q0 + 192) : q0;          // clamp: avoid OOB reads
        // 4x4 tile (i<=j): t{j}{i} = column w0+i of word-(w0+j) rows
        u64 t00 = FC(w0, q0);
        u64 t10 = (nwg > 1) ? FC(w0, q1) : 0ull;
        u64 t11 = (nwg > 1) ? FC(w0 + 1, q1) : 0ull;
        u64 t20 = (nwg > 2) ? FC(w0, q2) : 0ull;
        u64 t21 = (nwg > 2) ? FC(w0 + 1, q2) : 0ull;
        u64 t22 = (nwg > 2) ? FC(w0 + 2, q2) : 0ull;
        u64 t30 = (nwg > 3) ? FC(w0, q3) : 0ull;
        u64 t31 = (nwg > 3) ? FC(w0 + 1, q3) : 0ull;
        u64 t32 = (nwg > 3) ? FC(w0 + 2, q3) : 0ull;
        u64 t33 = (nwg > 3) ? FC(w0 + 3, q3) : 0ull;
        u64 v0 = validm[w0];
        u64 v1 = (nwg > 1) ? validm[w0 + 1] : 0ull;
        u64 v2 = (nwg > 2) ? validm[w0 + 2] : 0ull;
        u64 v3 = (nwg > 3) ? validm[w0 + 3] : 0ull;
        u64 sup0 = 0, sup1 = 0, sup2 = 0, sup3 = 0;
        bool dead = false;

        // fold over predecessor words [0, w0): 4-column x 4-row double-buffered
        // (aligned batches: batch at d0 covers words d0..d0+3, all < w0 since
        //  w0 is a multiple of 4; wait needs doneCnt >= d0/4 + 1)
        int d0 = 0;
        u64 a00=0,a01=0,a02=0,a03=0, a10=0,a11=0,a12=0,a13=0,
            a20=0,a21=0,a22=0,a23=0, a30=0,a31=0,a32=0,a33=0;  // a{j}{r}
        if (w0 > 0) {
            a00=LDC(0,0,0); a01=LDC(0,1,0); a02=LDC(0,2,0); a03=LDC(0,3,0);
            a10=LDC(1,0,0); a11=LDC(1,1,0); a12=LDC(1,2,0); a13=LDC(1,3,0);
            a20=LDC(2,0,0); a21=LDC(2,1,0); a22=LDC(2,2,0); a23=LDC(2,3,0);
            a30=LDC(3,0,0); a31=LDC(3,1,0); a32=LDC(3,2,0); a33=LDC(3,3,0);
        }
        asm volatile("" ::: "memory");   // pin load issue before the spin
        while (d0 < w0) {
            int d1 = d0 + 4;
            u64 b00=0,b01=0,b02=0,b03=0, b10=0,b11=0,b12=0,b13=0,
                b20=0,b21=0,b22=0,b23=0, b30=0,b31=0,b32=0,b33=0;
            if (d1 < w0) {
                b00=LDC(0,0,d1); b01=LDC(0,1,d1); b02=LDC(0,2,d1); b03=LDC(0,3,d1);
                b10=LDC(1,0,d1); b11=LDC(1,1,d1); b12=LDC(1,2,d1); b13=LDC(1,3,d1);
                b20=LDC(2,0,d1); b21=LDC(2,1,d1); b22=LDC(2,2,d1); b23=LDC(2,3,d1);
                b30=LDC(3,0,d1); b31=LDC(3,1,d1); b32=LDC(3,2,d1); b33=LDC(3,3,d1);
            }
            asm volatile("" ::: "memory");   // pin prefetch issue before the spin
            WAITG((d0 >> 2) + 1)             // group covering words d0..d0+3 final
            if (dead) break;
            u64 ka = keepAll[d0],     kb = keepAll[d0 + 1];
            u64 kc = keepAll[d0 + 2], kd = keepAll[d0 + 3];
            sup0 |= ((ka & a00) | (kb & a10)) | ((kc & a20) | (kd & a30));
            sup1 |= ((ka & a01) | (kb & a11)) | ((kc & a21) | (kd & a31));
            sup2 |= ((ka & a02) | (kb & a12)) | ((kc & a22) | (kd & a32));
            sup3 |= ((ka & a03) | (kb & a13)) | ((kc & a23) | (kd & a33));
            a00=b00;a01=b01;a02=b02;a03=b03; a10=b10;a11=b11;a12=b12;a13=b13;
            a20=b20;a21=b21;a22=b22;a23=b23; a30=b30;a31=b31;a32=b32;a33=b33;
            d0 = d1;
        }
        // all predecessors final & folded (last wait had need = G)
        if (!dead) {
            __builtin_amdgcn_s_setprio(1);   // favor the working wave vs spinners
            u32 tp = (G > 0) ? totG[G - 1] : 0u;
            u64 k0 = 0, k1 = 0, k2 = 0, k3 = 0;
            if (tp < POST_K) {
                k0 = nms_solve(v0, sup0, t00 & lmask);
                sup1 |= k0 & t10; sup2 |= k0 & t20; sup3 |= k0 & t30;
                k1 = nms_solve(v1, sup1, t11 & lmask);
                sup2 |= k1 & t21; sup3 |= k1 & t31;
                k2 = nms_solve(v2, sup2, t22 & lmask);
                sup3 |= k2 & t32;
                k3 = nms_solve(v3, sup3, t33 & lmask);
            }
            if (lane == 0) {
                keepAll[w0]     = k0;          // w0+3 <= 79 < 96: in-bounds
                keepAll[w0 + 1] = k1;
                keepAll[w0 + 2] = k2;
                keepAll[w0 + 3] = k3;
                u32 tk = tp + (u32)(__popcll(k0) + __popcll(k1) + __popcll(k2) + __popcll(k3));
                totG[G] = tk;
                asm volatile("s_waitcnt lgkmcnt(0)" ::: "memory");   // order LDS before flag
                __hip_atomic_store(&doneCnt,
                                   (tk >= POST_K) ? (u32)(NGRP + 9) : (u32)(G + 1),
                                   __ATOMIC_RELAXED, __HIP_MEMORY_SCOPE_WORKGROUP);
            }
            __builtin_amdgcn_s_setprio(0);
        } else {
            break;   // sentinel observed: all later groups dead too (keepAll stays 0)
        }
    }
    __syncthreads();

    // word-prefix ranks
    if (tid == 0) {
        u32 s = 0;
        for (int w = 0; w < NW; ++w) { wpref[w] = s; s += (u32)__popcll(keepAll[w]); }
        wpref[NW] = s;
    }
    __syncthreads();
    u32 totk = wpref[NW]; if (totk > POST_K) totk = POST_K;
    for (int r = tid; r < PRE_K; r += 512) {
        int w = r >> 6, b = r & 63;
        u64 kw = keepAll[w];
        if ((kw >> b) & 1ull) {
            u32 rank = wpref[w] + (u32)__popcll(kw & ((1ull << b) - 1ull));
            if (rank < POST_K) {
                const float* src = rows + (size_t)r * 16;
                float* dst = out + (size_t)rank * 15;
#pragma unroll
                for (int c2 = 0; c2 < 15; ++c2) dst[c2] = src[c2];
            }
        }
    }
    for (int r = (int)totk + tid; r < POST_K; r += 512) {
        float* dst = out + (size_t)r * 15;
#pragma unroll
        for (int c2 = 0; c2 < 15; ++c2) dst[c2] = 0.f;
    }
}

extern "C" void kernel_launch(void* const* d_in, const int* in_sizes, int n_in,
                              void* d_out, int out_size, void* d_ws, size_t ws_size,
                              hipStream_t stream) {
    const float* loc = (const float*)d_in[0];
    const float2* conf2 = (const float2*)d_in[1];
    const float* lmk = (const float*)d_in[2];
    const float* pri = (const float*)d_in[3];
    const int* imw = (const int*)d_in[4];
    const int* imh = (const int*)d_in[5];
    float* out = (float*)d_out;
    char* base = (char*)d_ws;

    // workspace layout (bytes); total 2,184,768 (< 3,808,896 proven in R3-R24)
    u32* hist   = (u32*)(base + 0);         //  32768  [zeroed by zero_kernel]
    u32* bfill  = (u32*)(base + 32768);     //  32768  [zeroed]
    u32* bsel   = (u32*)(base + 65536);     //  64     [zeroed]
    u64* validm = (u64*)(base + 65600);     //  1024   [zeroed]  -> zero [0,66624)
    u32* bstart = (u32*)(base + 67648);     //  32768
    u64* cand   = (u64*)(base + 100416);    //  65536
    float* rows = (float*)(base + 165952);  //  320000 (5000 x 16)
    float4* boxes = (float4*)(base + 485952); // 80896 (NPAD x 16)
    u64* cmask  = (u64*)(base + 566848);    //  1617920 (202240 u64, triangle-packed)

    zero_kernel<<<(ZBYTES / 4 + 255) / 256, 256, 0, stream>>>((u32*)base);

    hist_kernel<<<(N_IN + 255) / 256, 256, 0, stream>>>(conf2, hist);
    scan_kernel<<<1, 1024, 0, stream>>>(hist, bsel, bstart);
    compact_kernel<<<(N_IN + 255) / 256, 256, 0, stream>>>(conf2, bsel, bstart, bfill, cand);
    rankdec_kernel<<<48, 256, 0, stream>>>(cand, bstart, bfill, bsel, (const float4*)loc,
                                           (const float4*)pri, lmk, imw, imh,
                                           (float4*)rows, boxes, validm);
    mask_kernel<<<(NW * (NW + 1) / 2 + 3) / 4, 256, 0, stream>>>(boxes, cmask);
    reduce_scatter_kernel<<<1, 512, 0, stream>>>(cmask, validm, rows, out);
}